// Round 1
// 535.673 us; speedup vs baseline: 1.0171x; 1.0171x over previous
//
#include <hip/hip_runtime.h>

typedef unsigned short u16;
typedef u16   u16x4 __attribute__((ext_vector_type(4)));
typedef u16   u16x8 __attribute__((ext_vector_type(8)));
typedef short s16x8 __attribute__((ext_vector_type(8)));
typedef float f32x4 __attribute__((ext_vector_type(4)));

#define NSEQ 256
#define NRES 384
#define NF   64
#define NP   32
#define NO   128

__device__ __forceinline__ u16 f2b(float f) {
    union { float f; unsigned u; } c; c.f = f;
    unsigned r = c.u + 0x7fffu + ((c.u >> 16) & 1u);   // RNE
    return (u16)(r >> 16);
}

// async global->LDS, 16B per lane; LDS dest = wave-uniform base + lane*16
__device__ __forceinline__ void gload_lds16(const u16* g, u16* l) {
    __builtin_amdgcn_global_load_lds(
        (const __attribute__((address_space(1))) unsigned int*)(g),
        (__attribute__((address_space(3))) unsigned int*)(l),
        16, 0, 0);
}

// ---------------------------------------------------------------------------
// Kernel 0: convert Wo (f32, 128x1024) -> bf16 WoB, PERMUTED to the k' order
// used by k_main's Os layout:
//   k' = rg + l16*4 + ntb*64 + quad*128 + mtb*512
//   original cd = c*32 + d, c = mtb*16 + quad*4 + rg, d = ntb*16 + l16
// Grid 128 x 256; each thread emits 4 consecutive k' (one u16x4).
// ---------------------------------------------------------------------------
__global__ __launch_bounds__(256) void k_prep(const float* __restrict__ Wo,
                                              u16* __restrict__ WoB)
{
    int idx = blockIdx.x * 256 + threadIdx.x;          // [0, 32768)
    int o   = idx >> 8;                                // 256 threads per o-row
    int kp  = (idx & 255) << 2;                        // base k' (rg = 0..3)
    int l16 = (kp >> 2) & 15;
    int ntb = (kp >> 6) & 1;
    int qd  = (kp >> 7) & 3;
    int mtb = (kp >> 9) & 1;
    const float* src = Wo + o * 1024 + (mtb * 16 + qd * 4) * 32 + ntb * 16 + l16;
    u16x4 w;
    #pragma unroll
    for (int rg = 0; rg < 4; ++rg) w[rg] = f2b(src[rg * 32]);   // c advances with rg
    *(u16x4*)(WoB + o * 1024 + kp) = w;
}

// ---------------------------------------------------------------------------
// Kernel 1: LayerNorm + dual projection + mask -> leftT/rightT (bf16) in
// [ic = i*32+p][s] layout. Block 256 = residue i x 64 s. Grid (384, 4).
// (unchanged from previous version)
// ---------------------------------------------------------------------------
__global__ __launch_bounds__(256) void k_lnproj(
    const float* __restrict__ M, const float* __restrict__ mask,
    const float* __restrict__ gamma, const float* __restrict__ beta,
    const float* __restrict__ Wa, const float* __restrict__ ba,
    const float* __restrict__ Wb, const float* __restrict__ bb,
    u16* __restrict__ leftT, u16* __restrict__ rightT)
{
    __shared__ float Mt[64][68];        // [s][f], 272 B rows (16B-aligned)
    __shared__ float gs[64], bs[64], bias[64], mk[64];
    const int t  = threadIdx.x;
    const int i  = blockIdx.x;
    const int s0 = blockIdx.y * 64;
    const int s  = t >> 2, f0 = (t & 3) * 16;

    {   // stage M tile: thread -> 16 contiguous f (64 B)
        const float* g = M + ((long)(s0 + s) * NRES + i) * NF + f0;
        #pragma unroll
        for (int q = 0; q < 4; ++q) {
            f32x4 v = *(const f32x4*)(g + q * 4);
            #pragma unroll
            for (int e = 0; e < 4; ++e) Mt[s][f0 + q * 4 + e] = v[e];
        }
    }
    if (t < 64) { gs[t] = gamma[t]; bs[t] = beta[t];
                  mk[t] = mask[(long)(s0 + t) * NRES + i]; }
    if (t < 32) { bias[t] = ba[t]; bias[32 + t] = bb[t]; }
    __syncthreads();

    // LN stats: 4 threads per s, shfl_xor within aligned group-of-4
    float sum = 0.f, sq = 0.f;
    #pragma unroll
    for (int e = 0; e < 16; ++e) { float v = Mt[s][f0 + e]; sum += v; sq += v * v; }
    sum += __shfl_xor(sum, 1); sq += __shfl_xor(sq, 1);
    sum += __shfl_xor(sum, 2); sq += __shfl_xor(sq, 2);
    float mu  = sum * (1.f / 64.f);
    float var = sq * (1.f / 64.f) - mu * mu;
    float rs  = rsqrtf(var + 1e-5f);
    #pragma unroll
    for (int e = 0; e < 16; ++e) {
        int f = f0 + e;
        Mt[s][f] = (Mt[s][f] - mu) * rs * gs[f] + bs[f];
    }
    __syncthreads();

    // projection mapping: sg = wave (uniform), rowid = lane -> (lr, p)
    const int sg = t >> 6, rowid = t & 63;
    const int lr = rowid >> 5, p = rowid & 31;
    const float* Wg = (lr ? Wb : Wa) + p * 64;
    f32x4 wreg[16];
    #pragma unroll
    for (int q = 0; q < 16; ++q) wreg[q] = *(const f32x4*)(Wg + q * 4);

    float accv[16];
    #pragma unroll
    for (int e = 0; e < 16; ++e) accv[e] = 0.f;
    #pragma unroll 4
    for (int f4 = 0; f4 < 16; ++f4) {
        f32x4 w4 = wreg[f4];
        #pragma unroll
        for (int e = 0; e < 16; ++e) {
            f32x4 m4 = *(const f32x4*)(&Mt[sg * 16 + e][f4 * 4]);  // broadcast
            accv[e] += m4[0]*w4[0] + m4[1]*w4[1] + m4[2]*w4[2] + m4[3]*w4[3];
        }
    }
    const float b_ = bias[rowid];
    u16x8 o0, o1;
    #pragma unroll
    for (int e = 0; e < 8; ++e) o0[e] = f2b((accv[e]     + b_) * mk[sg * 16 + e]);
    #pragma unroll
    for (int e = 0; e < 8; ++e) o1[e] = f2b((accv[8 + e] + b_) * mk[sg * 16 + 8 + e]);
    u16* dst = (lr ? rightT : leftT) + ((long)i * NP + p) * NSEQ + s0 + sg * 16;
    *(u16x8*)dst       = o0;
    *(u16x8*)(dst + 8) = o1;
}

// ---------------------------------------------------------------------------
// Kernel 2: norm[i][j] = sum_s mask[s][i]*mask[s][j].  Grid (24,24) x 256.
// (unchanged)
// ---------------------------------------------------------------------------
__global__ __launch_bounds__(256) void k_norm(const float* __restrict__ mask,
                                              float* __restrict__ normMat)
{
    __shared__ float mi[256][17], mj[256][17];
    const int t  = threadIdx.x;
    const int iB = blockIdx.x * 16, jB = blockIdx.y * 16;
    #pragma unroll
    for (int it = 0; it < 16; ++it) {
        int ss = it * 16 + (t >> 4);
        int c  = t & 15;
        mi[ss][c] = mask[(long)ss * NRES + iB + c];
        mj[ss][c] = mask[(long)ss * NRES + jB + c];
    }
    __syncthreads();
    const int ti = t >> 4, tj = t & 15;
    float acc = 0.f;
    for (int ss = 0; ss < 256; ++ss) acc += mi[ss][ti] * mj[ss][tj];
    normMat[(long)(iB + ti) * NRES + jB + tj] = acc;
}

// ---------------------------------------------------------------------------
// Kernel 3: fused outer-product GEMM, 256x128 tile, 8 waves (512 thr).
//  - stage 1: K=256 in 8 steps of 32, double-buffered async LDS staging with
//    prefetch issued BEFORE compute (loads in flight during ds_read+MFMA).
//  - Os overlay: [pair 0..31][k' 0..1023] bf16, XOR-swizzled, b64 writes.
//  - stage 2: Z2[pair][o], K=1024 against permuted WoB (L2-hot).
//  LDS = 64 KB; __launch_bounds__(512,4) targets 2 blocks/CU so one block's
//  L2-bound stage 2 overlaps the other's MFMA-bound stage 1.
//  Grid: 4608 x 512, 1-D; XCD-chunked swizzle (4608 % 8 == 0 -> bijective).
// ---------------------------------------------------------------------------
__global__ __launch_bounds__(512, 4) void k_main(
    const u16* __restrict__ leftT, const u16* __restrict__ rightT,
    const float* __restrict__ normMat,
    const u16* __restrict__ WoB, const float* __restrict__ bo,
    const float* __restrict__ Zraw, float* __restrict__ out)
{
    // staging: A dbuf [2][256*32] u16 @ 0 / 8192 ; B dbuf [2][128*32] @ 16384 / 20480
    // Os overlay: [32 pairs][1024 k'] u16 = 32768 u16 (full 64 KB)
    __shared__ __align__(16) u16 smem[32768];

    const int t    = threadIdx.x;
    const int wave = t >> 6, lane = t & 63;
    const int quad = lane >> 4, l16 = lane & 15;
    const int wr = wave >> 1, wc = wave & 1;         // 4 x 2 wave grid, 64x64 each

    // XCD-chunked block swizzle: each XCD gets 576 consecutive tiles (12 by-rows)
    const int bid = blockIdx.x;
    const int w   = (bid & 7) * 576 + (bid >> 3);
    const int by  = w / 48, bx = w % 48;             // bx: 48 ic-tiles, by: 96 jd-tiles
    const int icBase = bx * 256;
    const int jdBase = by * 128;

    const int srow = lane >> 2, sc8 = (lane & 3) * 8;

    f32x4 acc[4][4] = {};

    // per-lane global staging sources (A: 2 segs of 16 rows; B: 1 seg)
    const u16* aSrc0 = leftT  + (icBase + wave * 32 + srow) * NSEQ + sc8;
    const u16* aSrc1 = aSrc0 + 16 * NSEQ;
    const u16* bSrc  = rightT + (jdBase + wave * 16 + srow) * NSEQ + sc8;

    #define STAGE(buf, k0) do {                                                  \
        gload_lds16(aSrc0 + (k0), &smem[(buf) * 8192 + wave * 1024]);            \
        gload_lds16(aSrc1 + (k0), &smem[(buf) * 8192 + wave * 1024 + 512]);      \
        gload_lds16(bSrc  + (k0), &smem[16384 + (buf) * 4096 + wave * 512]);     \
    } while (0)

    STAGE(0, 0);
    __syncthreads();                                 // buf0 ready

    #pragma unroll
    for (int kt = 0; kt < 8; ++kt) {
        const int cur = kt & 1;
        if (kt < 7) STAGE(cur ^ 1, (kt + 1) * 32);   // prefetch in flight during compute

        u16x8 af[4], bf[4];
        const u16* Ab = &smem[cur * 8192 + (wr * 64 + l16) * 32 + quad * 8];
        const u16* Bb = &smem[16384 + cur * 4096 + (wc * 64 + l16) * 32 + quad * 8];
        #pragma unroll
        for (int mt = 0; mt < 4; ++mt) af[mt] = *(const u16x8*)(Ab + mt * 512);
        #pragma unroll
        for (int nt = 0; nt < 4; ++nt) bf[nt] = *(const u16x8*)(Bb + nt * 512);

        #pragma unroll
        for (int mt = 0; mt < 4; ++mt)
            #pragma unroll
            for (int nt = 0; nt < 4; ++nt)
                acc[mt][nt] = __builtin_amdgcn_mfma_f32_16x16x32_bf16(
                    (s16x8)af[mt], (s16x8)bf[nt], acc[mt][nt], 0, 0, 0);

        __syncthreads();                             // drains prefetch + read fence
    }

    // ---- O tile -> Os overlay [pair][k'], swizzled; b64 writes -------------
    // thread element: ic = wr*64 + mt*16 + quad*4 + rg, jd = wc*64 + nt*16 + l16
    // k' = rg + l16*4 + (nt&1)*64 + quad*128 + (mt&1)*512  (rg contiguous)
    // stored at pair*1024 + (k' ^ (quad<<4) ^ ((pair&7)<<3))
    #pragma unroll
    for (int mt = 0; mt < 4; ++mt) {
        #pragma unroll
        for (int nt = 0; nt < 4; ++nt) {
            int pair = (wr * 2 + (mt >> 1)) * 4 + wc * 2 + (nt >> 1);
            int kp   = l16 * 4 + (nt & 1) * 64 + quad * 128 + (mt & 1) * 512;
            int ks   = kp ^ (quad << 4) ^ ((pair & 7) << 3);
            u16x4 wv;
            #pragma unroll
            for (int rg = 0; rg < 4; ++rg) wv[rg] = f2b(acc[mt][nt][rg]);
            *(u16x4*)&smem[pair * 1024 + ks] = wv;
        }
    }
    __syncthreads();

    // ---- stage 2: Z2[pair][o] = sum_k' Os[pair][k'] * WoB[o][k'] -----------
    // 8 waves: m-tile = wave>>2 (pairs mbase..mbase+15), o-block = (wave&3)*32
    f32x4 acc2[2] = {};
    const int mbase  = (wave >> 2) * 16;
    const int ob     = (wave & 3) * 32;
    const int pair_m = mbase + l16;
    const int osbase = pair_m * 1024;
    const int pxor   = (pair_m & 7) << 3;
    const u16* wp0 = WoB + (ob + l16) * 1024 + quad * 8;
    const u16* wp1 = wp0 + 16 * 1024;
    #pragma unroll 4
    for (int kk = 0; kk < 32; ++kk) {
        int kp = kk * 32 + quad * 8;
        int ks = kp ^ (((kp >> 7) & 3) << 4) ^ pxor;
        u16x8 a2 = *(const u16x8*)&smem[osbase + ks];
        u16x8 b0 = *(const u16x8*)(wp0 + kk * 32);
        u16x8 b1 = *(const u16x8*)(wp1 + kk * 32);
        acc2[0] = __builtin_amdgcn_mfma_f32_16x16x32_bf16((s16x8)a2, (s16x8)b0, acc2[0], 0, 0, 0);
        acc2[1] = __builtin_amdgcn_mfma_f32_16x16x32_bf16((s16x8)a2, (s16x8)b1, acc2[1], 0, 0, 0);
    }

    // ---- epilogue: (z + bo)/(0.001+norm) + Zraw ----------------------------
    const int i0 = bx * 8, j0 = by * 4;
    #pragma unroll
    for (int nt = 0; nt < 2; ++nt) {
        int o = ob + nt * 16 + l16;
        float bov = bo[o];
        #pragma unroll
        for (int rg = 0; rg < 4; ++rg) {
            int pr = mbase + quad * 4 + rg;            // D row = pair
            int i = i0 + (pr >> 2), j = j0 + (pr & 3);
            float nrm = normMat[i * NRES + j];
            long off = ((long)(i * NRES + j)) * NO + o;
            out[off] = (acc2[nt][rg] + bov) / (0.001f + nrm) + Zraw[off];
        }
    }
    #undef STAGE
}

extern "C" void kernel_launch(void* const* d_in, const int* in_sizes, int n_in,
                              void* d_out, int out_size, void* d_ws, size_t ws_size,
                              hipStream_t stream)
{
    const float* M     = (const float*)d_in[0];
    const float* mask  = (const float*)d_in[1];
    const float* Zraw  = (const float*)d_in[2];
    const float* gamma = (const float*)d_in[3];
    const float* beta  = (const float*)d_in[4];
    const float* Wa    = (const float*)d_in[5];
    const float* ba    = (const float*)d_in[6];
    const float* Wb    = (const float*)d_in[7];
    const float* bb    = (const float*)d_in[8];
    const float* Wo    = (const float*)d_in[9];
    const float* bo    = (const float*)d_in[10];
    float* out = (float*)d_out;

    char* ws = (char*)d_ws;
    u16*   leftT   = (u16*)ws;                      // 12288 x 256 bf16
    u16*   rightT  = (u16*)(ws + 6291456);
    float* normMat = (float*)(ws + 12582912);       // 384x384 f32
    u16*   WoB     = (u16*)(ws + 13172736);         // 128x1024 bf16 (k'-permuted)

    k_prep<<<dim3(128), dim3(256), 0, stream>>>(Wo, WoB);
    k_lnproj<<<dim3(NRES, 4), dim3(256), 0, stream>>>(M, mask, gamma, beta,
                                                      Wa, ba, Wb, bb, leftT, rightT);
    k_norm<<<dim3(24, 24), dim3(256), 0, stream>>>(mask, normMat);
    k_main<<<dim3(4608), dim3(512), 0, stream>>>(leftT, rightT, normMat,
                                                 WoB, bo, Zraw, out);
}

// Round 2
// 387.538 us; speedup vs baseline: 1.4059x; 1.3822x over previous
//
#include <hip/hip_runtime.h>

typedef unsigned short u16;
typedef u16   u16x4 __attribute__((ext_vector_type(4)));
typedef u16   u16x8 __attribute__((ext_vector_type(8)));
typedef short s16x8 __attribute__((ext_vector_type(8)));
typedef float f32x4 __attribute__((ext_vector_type(4)));

#define NSEQ 256
#define NRES 384
#define NF   64
#define NP   32
#define NO   128

__device__ __forceinline__ u16 f2b(float f) {
    union { float f; unsigned u; } c; c.f = f;
    unsigned r = c.u + 0x7fffu + ((c.u >> 16) & 1u);   // RNE
    return (u16)(r >> 16);
}

// async global->LDS, 16B per lane; LDS dest = wave-uniform base + lane*16
__device__ __forceinline__ void gload_lds16(const u16* g, u16* l) {
    __builtin_amdgcn_global_load_lds(
        (const __attribute__((address_space(1))) unsigned int*)(g),
        (__attribute__((address_space(3))) unsigned int*)(l),
        16, 0, 0);
}

// ---------------------------------------------------------------------------
// k_pre: merged {lnproj (blocks 0..1535), Wo-prep (1536..1663), norm (1664..2239)}
// All roles are 256-thread blocks; one launch saves 2 launch gaps.
// ---------------------------------------------------------------------------
__global__ __launch_bounds__(256) void k_pre(
    const float* __restrict__ M, const float* __restrict__ mask,
    const float* __restrict__ gamma, const float* __restrict__ beta,
    const float* __restrict__ Wa, const float* __restrict__ ba,
    const float* __restrict__ Wb, const float* __restrict__ bb,
    const float* __restrict__ Wo,
    u16* __restrict__ leftT, u16* __restrict__ rightT,
    float* __restrict__ normMat, u16* __restrict__ WoB)
{
    __shared__ __align__(16) char sm[34816];
    const int b = blockIdx.x, t = threadIdx.x;

    if (b < 1536) {
        // ---------------- LayerNorm + dual projection ----------------------
        float (*Mt)[68] = (float (*)[68])sm;            // 64 x 68 f32 = 17408 B
        float* gs   = (float*)(sm + 17408);
        float* bs   = gs + 64;
        float* bias = bs + 64;
        float* mk   = bias + 64;
        const int i  = b % NRES;
        const int s0 = (b / NRES) * 64;
        const int s  = t >> 2, f0 = (t & 3) * 16;

        {   // stage M tile: thread -> 16 contiguous f (64 B)
            const float* g = M + ((long)(s0 + s) * NRES + i) * NF + f0;
            #pragma unroll
            for (int q = 0; q < 4; ++q) {
                f32x4 v = *(const f32x4*)(g + q * 4);
                #pragma unroll
                for (int e = 0; e < 4; ++e) Mt[s][f0 + q * 4 + e] = v[e];
            }
        }
        if (t < 64) { gs[t] = gamma[t]; bs[t] = beta[t];
                      mk[t] = mask[(long)(s0 + t) * NRES + i]; }
        if (t < 32) { bias[t] = ba[t]; bias[32 + t] = bb[t]; }
        __syncthreads();

        float sum = 0.f, sq = 0.f;
        #pragma unroll
        for (int e = 0; e < 16; ++e) { float v = Mt[s][f0 + e]; sum += v; sq += v * v; }
        sum += __shfl_xor(sum, 1); sq += __shfl_xor(sq, 1);
        sum += __shfl_xor(sum, 2); sq += __shfl_xor(sq, 2);
        float mu  = sum * (1.f / 64.f);
        float var = sq * (1.f / 64.f) - mu * mu;
        float rs  = rsqrtf(var + 1e-5f);
        #pragma unroll
        for (int e = 0; e < 16; ++e) {
            int f = f0 + e;
            Mt[s][f] = (Mt[s][f] - mu) * rs * gs[f] + bs[f];
        }
        __syncthreads();

        const int sg = t >> 6, rowid = t & 63;
        const int lr = rowid >> 5, p = rowid & 31;
        const float* Wg = (lr ? Wb : Wa) + p * 64;
        f32x4 wreg[16];
        #pragma unroll
        for (int q = 0; q < 16; ++q) wreg[q] = *(const f32x4*)(Wg + q * 4);

        float accv[16];
        #pragma unroll
        for (int e = 0; e < 16; ++e) accv[e] = 0.f;
        #pragma unroll 4
        for (int f4 = 0; f4 < 16; ++f4) {
            f32x4 w4 = wreg[f4];
            #pragma unroll
            for (int e = 0; e < 16; ++e) {
                f32x4 m4 = *(const f32x4*)(&Mt[sg * 16 + e][f4 * 4]);  // broadcast
                accv[e] += m4[0]*w4[0] + m4[1]*w4[1] + m4[2]*w4[2] + m4[3]*w4[3];
            }
        }
        const float b_ = bias[rowid];
        u16x8 o0, o1;
        #pragma unroll
        for (int e = 0; e < 8; ++e) o0[e] = f2b((accv[e]     + b_) * mk[sg * 16 + e]);
        #pragma unroll
        for (int e = 0; e < 8; ++e) o1[e] = f2b((accv[8 + e] + b_) * mk[sg * 16 + 8 + e]);
        u16* dst = (lr ? rightT : leftT) + ((long)i * NP + p) * NSEQ + s0 + sg * 16;
        *(u16x8*)dst       = o0;
        *(u16x8*)(dst + 8) = o1;

    } else if (b < 1664) {
        // ---------------- Wo f32 -> bf16, k'-permuted -----------------------
        // k' = rg + l16*4 + ntb*64 + quad*128 + mtb*512 ; cd = c*32 + d,
        // c = mtb*16 + quad*4 + rg, d = ntb*16 + l16
        int idx = (b - 1536) * 256 + t;                // [0, 32768)
        int o   = idx >> 8;
        int kp  = (idx & 255) << 2;
        int l16 = (kp >> 2) & 15;
        int ntb = (kp >> 6) & 1;
        int qd  = (kp >> 7) & 3;
        int mtb = (kp >> 9) & 1;
        const float* src = Wo + o * 1024 + (mtb * 16 + qd * 4) * 32 + ntb * 16 + l16;
        u16x4 w;
        #pragma unroll
        for (int rg = 0; rg < 4; ++rg) w[rg] = f2b(src[rg * 32]);
        *(u16x4*)(WoB + o * 1024 + kp) = w;

    } else {
        // ---------------- norm[i][j] = sum_s mask[s][i]*mask[s][j] ----------
        float (*mi)[17] = (float (*)[17])sm;
        float (*mj)[17] = (float (*)[17])(sm + 17408);
        const int bn = b - 1664;
        const int iB = (bn / 24) * 16, jB = (bn % 24) * 16;
        #pragma unroll
        for (int it = 0; it < 16; ++it) {
            int ss = it * 16 + (t >> 4);
            int c  = t & 15;
            mi[ss][c] = mask[(long)ss * NRES + iB + c];
            mj[ss][c] = mask[(long)ss * NRES + jB + c];
        }
        __syncthreads();
        const int ti = t >> 4, tj = t & 15;
        float acc = 0.f;
        for (int ss = 0; ss < 256; ++ss) acc += mi[ss][ti] * mj[ss][tj];
        normMat[(long)(iB + ti) * NRES + jB + tj] = acc;
    }
}

// ---------------------------------------------------------------------------
// k_main: 256x128 tile, 8 waves. Counted-vmcnt pipeline (T3+T4): next-tile
// global_load_lds stays in flight across the barrier; only the wave's own
// 3 current-tile loads are waited on (vmcnt(3)), then raw s_barrier.
// Stage-2 shares the Wo B-frag across both m-tiles (Wo traffic halved) and
// the epilogue round-trips Z2 through LDS for fully-coalesced 2 KB stores.
// Staging uses a k-granule XOR swizzle (g ^= (row>>1)&3) applied on the
// GLOBAL source (T21) so ds_read_b128 spreads 2 lanes/bank-slot instead of 8.
// ---------------------------------------------------------------------------
__global__ __launch_bounds__(512, 4) void k_main(
    const u16* __restrict__ leftT, const u16* __restrict__ rightT,
    const float* __restrict__ normMat,
    const u16* __restrict__ WoB, const float* __restrict__ bo,
    const float* __restrict__ Zraw, float* __restrict__ out)
{
    // A dbuf [2][256*32] @ 0/8192 ; B dbuf [2][128*32] @ 16384/20480 (u16 idx)
    // Os overlay [32 pairs][1024 k'] u16 = full 64 KB; Z2 overlay f32[32][128]
    __shared__ __align__(16) u16 smem[32768];

    const int t    = threadIdx.x;
    const int wave = t >> 6, lane = t & 63;
    const int quad = lane >> 4, l16 = lane & 15;
    const int wr = wave >> 1, wc = wave & 1;         // 4 x 2 wave grid, 64x64

    // XCD-local mapping: xcd = bid&7 owns by in [xcd*12, xcd*12+12);
    // 12 consecutive blocks inside an XCD share one A-panel (bx).
    // Per-XCD L2 working set: 12 B-panels (~0.8 MB) + A-window (~0.8 MB).
    const int bid = blockIdx.x;
    const int r_  = bid >> 3;                        // 0..575
    const int bx  = r_ / 12;                         // 0..47
    const int by  = (bid & 7) * 12 + (r_ % 12);      // 0..95
    const int icBase = bx * 256;
    const int jdBase = by * 128;

    const int srow = lane >> 2;
    const int g8   = ((lane & 3) ^ ((srow >> 1) & 3)) * 8;   // swizzled k-granule

    f32x4 acc[4][4] = {};

    const u16* aSrc0 = leftT  + (icBase + wave * 32 + srow) * NSEQ + g8;
    const u16* aSrc1 = aSrc0 + 16 * NSEQ;
    const u16* bSrc  = rightT + (jdBase + wave * 16 + srow) * NSEQ + g8;

    #define STAGE(buf, k0) do {                                                  \
        gload_lds16(aSrc0 + (k0), &smem[(buf) * 8192 + wave * 1024]);            \
        gload_lds16(aSrc1 + (k0), &smem[(buf) * 8192 + wave * 1024 + 512]);      \
        gload_lds16(bSrc  + (k0), &smem[16384 + (buf) * 4096 + wave * 512]);     \
    } while (0)

    STAGE(0, 0);                                     // 3 loads in flight

    #pragma unroll
    for (int kt = 0; kt < 8; ++kt) {
        const int cur = kt & 1;
        if (kt < 7) {
            STAGE(cur ^ 1, (kt + 1) * 32);           // +3 -> 6 in flight
            asm volatile("s_waitcnt vmcnt(3)" ::: "memory");  // cur tile landed
        } else {
            asm volatile("s_waitcnt vmcnt(0)" ::: "memory");
        }
        __builtin_amdgcn_s_barrier();                // all waves' cur data in LDS
        __builtin_amdgcn_sched_barrier(0);

        const int gx = (quad ^ ((l16 >> 1) & 3)) * 8;        // de-swizzle read
        u16x8 af[4], bf[4];
        const u16* Ab = &smem[cur * 8192 + (wr * 64 + l16) * 32 + gx];
        const u16* Bb = &smem[16384 + cur * 4096 + (wc * 64 + l16) * 32 + gx];
        #pragma unroll
        for (int mt = 0; mt < 4; ++mt) af[mt] = *(const u16x8*)(Ab + mt * 512);
        #pragma unroll
        for (int nt = 0; nt < 4; ++nt) bf[nt] = *(const u16x8*)(Bb + nt * 512);

        #pragma unroll
        for (int mt = 0; mt < 4; ++mt)
            #pragma unroll
            for (int nt = 0; nt < 4; ++nt)
                acc[mt][nt] = __builtin_amdgcn_mfma_f32_16x16x32_bf16(
                    (s16x8)af[mt], (s16x8)bf[nt], acc[mt][nt], 0, 0, 0);

        __builtin_amdgcn_sched_barrier(0);
        __builtin_amdgcn_s_barrier();                // arrival-only: reads done,
    }                                                // next STAGE may overwrite
    #undef STAGE

    // ---- O tile -> Os overlay [pair][k'], swizzled; b64 writes -------------
    // ic = wr*64 + mt*16 + quad*4 + rg, jd = wc*64 + nt*16 + l16
    // k' = rg + l16*4 + (nt&1)*64 + quad*128 + (mt&1)*512
    // addr = pair*1024 + (k' ^ ((k'>>7 & 3)<<4) ^ ((pair&7)<<3))
    #pragma unroll
    for (int mt = 0; mt < 4; ++mt) {
        #pragma unroll
        for (int nt = 0; nt < 4; ++nt) {
            int pair = (wr * 2 + (mt >> 1)) * 4 + wc * 2 + (nt >> 1);
            int kp   = l16 * 4 + (nt & 1) * 64 + quad * 128 + (mt & 1) * 512;
            int ks   = kp ^ (quad << 4) ^ ((pair & 7) << 3);
            u16x4 wv;
            #pragma unroll
            for (int rg = 0; rg < 4; ++rg) wv[rg] = f2b(acc[mt][nt][rg]);
            *(u16x4*)&smem[pair * 1024 + ks] = wv;
        }
    }
    __syncthreads();

    // ---- stage 2: Z2[pair][o], B-frag shared across both m-tiles -----------
    // wave -> o-range [wave*16, wave*16+16); per kk: 2 ds_read + 1 Wo + 2 MFMA
    f32x4 acc2[2] = {};
    const int ob   = wave * 16;
    const int pxor = (l16 & 7) << 3;                 // (pair&7) same for both tiles
    const u16* wp  = WoB + (ob + l16) * 1024 + quad * 8;
    const u16* os0 = &smem[l16 * 1024];              // pair = l16
    const u16* os1 = &smem[(16 + l16) * 1024];       // pair = 16 + l16
    #pragma unroll 4
    for (int kk = 0; kk < 32; ++kk) {
        int kp = kk * 32 + quad * 8;
        int ks = kp ^ (((kp >> 7) & 3) << 4) ^ pxor;
        u16x8 a0 = *(const u16x8*)(os0 + ks);
        u16x8 a1 = *(const u16x8*)(os1 + ks);
        u16x8 bv = *(const u16x8*)(wp + kk * 32);
        acc2[0] = __builtin_amdgcn_mfma_f32_16x16x32_bf16((s16x8)a0, (s16x8)bv, acc2[0], 0, 0, 0);
        acc2[1] = __builtin_amdgcn_mfma_f32_16x16x32_bf16((s16x8)a1, (s16x8)bv, acc2[1], 0, 0, 0);
    }
    __syncthreads();                                 // all Os reads done

    // ---- Z2 -> LDS f32 [32][128] for coalesced epilogue --------------------
    float* zs = (float*)smem;
    #pragma unroll
    for (int m = 0; m < 2; ++m)
        #pragma unroll
        for (int rg = 0; rg < 4; ++rg)
            zs[(m * 16 + quad * 4 + rg) * 128 + ob + l16] = acc2[m][rg];
    __syncthreads();

    // ---- epilogue: one wave stores 2 KB contiguous (pr 0..3 -> adjacent j) -
    const int i0 = bx * 8, j0 = by * 4;
    const int pr = t >> 4, o0 = (t & 15) * 8;
    const int i = i0 + (pr >> 2), j = j0 + (pr & 3);
    const float rn = 1.f / (0.001f + normMat[i * NRES + j]);
    const long base = ((long)(i * NRES + j)) * NO + o0;
    f32x4 z0  = *(const f32x4*)&zs[pr * 128 + o0];
    f32x4 z1  = *(const f32x4*)&zs[pr * 128 + o0 + 4];
    f32x4 zr0 = *(const f32x4*)(Zraw + base);
    f32x4 zr1 = *(const f32x4*)(Zraw + base + 4);
    f32x4 bv0 = *(const f32x4*)(bo + o0);
    f32x4 bv1 = *(const f32x4*)(bo + o0 + 4);
    f32x4 r0, r1;
    #pragma unroll
    for (int e = 0; e < 4; ++e) r0[e] = (z0[e] + bv0[e]) * rn + zr0[e];
    #pragma unroll
    for (int e = 0; e < 4; ++e) r1[e] = (z1[e] + bv1[e]) * rn + zr1[e];
    *(f32x4*)(out + base)     = r0;
    *(f32x4*)(out + base + 4) = r1;
}

extern "C" void kernel_launch(void* const* d_in, const int* in_sizes, int n_in,
                              void* d_out, int out_size, void* d_ws, size_t ws_size,
                              hipStream_t stream)
{
    const float* M     = (const float*)d_in[0];
    const float* mask  = (const float*)d_in[1];
    const float* Zraw  = (const float*)d_in[2];
    const float* gamma = (const float*)d_in[3];
    const float* beta  = (const float*)d_in[4];
    const float* Wa    = (const float*)d_in[5];
    const float* ba    = (const float*)d_in[6];
    const float* Wb    = (const float*)d_in[7];
    const float* bb    = (const float*)d_in[8];
    const float* Wo    = (const float*)d_in[9];
    const float* bo    = (const float*)d_in[10];
    float* out = (float*)d_out;

    char* ws = (char*)d_ws;
    u16*   leftT   = (u16*)ws;                      // 12288 x 256 bf16
    u16*   rightT  = (u16*)(ws + 6291456);
    float* normMat = (float*)(ws + 12582912);       // 384x384 f32
    u16*   WoB     = (u16*)(ws + 13172736);         // 128x1024 bf16 (k'-permuted)

    k_pre<<<dim3(2240), dim3(256), 0, stream>>>(M, mask, gamma, beta,
                                                Wa, ba, Wb, bb, Wo,
                                                leftT, rightT, normMat, WoB);
    k_main<<<dim3(4608), dim3(512), 0, stream>>>(leftT, rightT, normMat,
                                                 WoB, bo, Zraw, out);
}

// Round 3
// 341.785 us; speedup vs baseline: 1.5941x; 1.1339x over previous
//
#include <hip/hip_runtime.h>

typedef unsigned short u16;
typedef u16   u16x4 __attribute__((ext_vector_type(4)));
typedef u16   u16x8 __attribute__((ext_vector_type(8)));
typedef short s16x8 __attribute__((ext_vector_type(8)));
typedef float f32x4 __attribute__((ext_vector_type(4)));

#define NSEQ 256
#define NRES 384
#define NF   64
#define NP   32
#define NO   128

__device__ __forceinline__ u16 f2b(float f) {
    union { float f; unsigned u; } c; c.f = f;
    unsigned r = c.u + 0x7fffu + ((c.u >> 16) & 1u);   // RNE
    return (u16)(r >> 16);
}
__device__ __forceinline__ float b2f(u16 h) {
    union { unsigned u; float f; } c; c.u = ((unsigned)h) << 16;
    return c.f;
}

// async global->LDS, 16B per lane; LDS dest = wave-uniform base + lane*16,
// global source address is PER-LANE (enables pre-swizzled-source T21 layouts)
__device__ __forceinline__ void gload_lds16(const u16* g, u16* l) {
    __builtin_amdgcn_global_load_lds(
        (const __attribute__((address_space(1))) unsigned int*)(g),
        (__attribute__((address_space(3))) unsigned int*)(l),
        16, 0, 0);
}

// ---------------------------------------------------------------------------
// k_pre: merged pre-processing.
//   blocks [0,768)     : lnproj REWRITTEN — 16 i x 8 s per block, DMA staging,
//                        reg-LN, split-precision bf16 MFMA projection
//   blocks [768,896)   : Wo f32 -> bf16 k'-permuted (unchanged body)
//   blocks [896,1472)  : norm matrix (unchanged body)
// ---------------------------------------------------------------------------
__global__ __launch_bounds__(256) void k_pre(
    const float* __restrict__ M, const float* __restrict__ mask,
    const float* __restrict__ gamma, const float* __restrict__ beta,
    const float* __restrict__ Wa, const float* __restrict__ ba,
    const float* __restrict__ Wb, const float* __restrict__ bb,
    const float* __restrict__ Wo,
    u16* __restrict__ leftT, u16* __restrict__ rightT,
    float* __restrict__ normMat, u16* __restrict__ WoB)
{
    // region map (bytes):
    //   [0, 32768)       Mraw f32 [128 rows][64]  -> overlay: hi plane u16[128][64] @0,
    //                                                lo plane u16[128][64] @16384
    //   [32768, 51200)   W planes u16 [side2*plane2][32 p][72]   (18432 B)
    //   [51200, 51712)   mk   f32[128]
    //   [51712, 51968)   bias f32[64]   (ba | bb)
    //   [51968, 52224)   gamma f32[64]
    //   [52224, 52480)   beta  f32[64]
    __shared__ __align__(16) char sm[52480];
    const int b = blockIdx.x, t = threadIdx.x;

    if (b < 768) {
        // ---------------- LayerNorm + dual projection (MFMA) ----------------
        // rows r = ii*8 + s  (ii in [0,16), s in [0,8));  i = i0+ii, seq = s0+s
        const int sC = b / 24, iC = b % 24;
        const int i0 = iC * 16, s0 = sC * 8;

        u16*   hiP   = (u16*)sm;                 // overlay after raw consumed
        u16*   loP   = (u16*)sm + 8192;
        u16*   WP    = (u16*)(sm + 32768);
        float* mkP   = (float*)(sm + 51200);
        float* biasP = (float*)(sm + 51712);
        float* glP   = (float*)(sm + 51968);
        float* blP   = (float*)(sm + 52224);

        const int wv = t >> 6, ln = t & 63;
        const int quad = ln >> 4, l16 = ln & 15;

        // -- DMA stage Mraw: LDS granule (r,c) <- M granule (r, c^xsw(r)) ----
        {
            const int rl = ln >> 4, c = ln & 15;
            #pragma unroll
            for (int q = 0; q < 8; ++q) {
                int rbase = wv * 32 + q * 4;
                int r   = rbase + rl;
                int xsw = (r & 3) << 1;                       // even: pair-preserving
                const float* src = M + ((long)(s0 + (r & 7)) * NRES + (i0 + (r >> 3))) * NF
                                     + ((c ^ xsw) << 2);
                gload_lds16((const u16*)src, (u16*)sm + rbase * 128);
            }
        }
        // -- stage W split planes, mask, bias, gamma/beta --------------------
        {
            const int side = t >> 7, p = (t >> 2) & 31, qq = t & 3;
            const float* Wg = (side ? Wb : Wa) + p * 64 + qq * 16;
            u16x8 h[2], l[2];
            #pragma unroll
            for (int u = 0; u < 4; ++u) {
                f32x4 w4 = *(const f32x4*)(Wg + u * 4);
                #pragma unroll
                for (int e = 0; e < 4; ++e) {
                    u16 hb = f2b(w4[e]);
                    h[u >> 1][(u & 1) * 4 + e] = hb;
                    l[u >> 1][(u & 1) * 4 + e] = f2b(w4[e] - b2f(hb));
                }
            }
            int hbase = ((side * 2 + 0) * 32 + p) * 72 + qq * 16;
            int lbase = ((side * 2 + 1) * 32 + p) * 72 + qq * 16;
            *(u16x8*)(WP + hbase)     = h[0];
            *(u16x8*)(WP + hbase + 8) = h[1];
            *(u16x8*)(WP + lbase)     = l[0];
            *(u16x8*)(WP + lbase + 8) = l[1];
        }
        if (t < 128) mkP[t] = mask[(long)(s0 + (t & 7)) * NRES + i0 + (t >> 3)];
        if (t < 64) { glP[t] = gamma[t]; blP[t] = beta[t];
                      biasP[t] = (t < 32) ? ba[t] : bb[t - 32]; }
        __syncthreads();                                  // DMA + stages visible

        // -- LN: thread owns half a row (32 floats) in regs ------------------
        const int r = t >> 1, half = t & 1;
        const int xsw = (r & 3) << 1, psw = r & 3;
        f32x4 v[8];
        {
            const float* raw = (const float*)sm + r * 64;
            #pragma unroll
            for (int e = 0; e < 8; ++e)
                v[e] = *(const f32x4*)(raw + (((half * 8 + e) ^ xsw) << 2));
        }
        float sum = 0.f, sq = 0.f;
        #pragma unroll
        for (int e = 0; e < 8; ++e)
            #pragma unroll
            for (int j = 0; j < 4; ++j) { float x = v[e][j]; sum += x; sq += x * x; }
        sum += __shfl_xor(sum, 1); sq += __shfl_xor(sq, 1);
        float mu  = sum * (1.f / 64.f);
        float var = sq * (1.f / 64.f) - mu * mu;
        float rs  = rsqrtf(var + 1e-5f);
        #pragma unroll
        for (int e = 0; e < 8; ++e) {                     // v[e] = ORIG granule half*8+e
            int og = half * 8 + e;
            f32x4 g4 = *(const f32x4*)(glP + og * 4);
            f32x4 b4 = *(const f32x4*)(blP + og * 4);
            #pragma unroll
            for (int j = 0; j < 4; ++j) v[e][j] = (v[e][j] - mu) * rs * g4[j] + b4[j];
        }
        __syncthreads();                                  // all raw reads done

        // -- write hi/lo planes (overlay); granule q holds pg = q ^ psw ------
        #pragma unroll
        for (int d = 0; d < 4; ++d) {
            u16x8 h8, l8;
            #pragma unroll
            for (int j = 0; j < 4; ++j) {
                u16 hb = f2b(v[2 * d][j]);
                h8[j] = hb; l8[j] = f2b(v[2 * d][j] - b2f(hb));
                u16 hb2 = f2b(v[2 * d + 1][j]);
                h8[4 + j] = hb2; l8[4 + j] = f2b(v[2 * d + 1][j] - b2f(hb2));
            }
            int q = (half * 4 + d) ^ psw;
            *(u16x8*)(hiP + r * 64 + q * 8) = h8;
            *(u16x8*)(loP + r * 64 + q * 8) = l8;
        }
        __syncthreads();

        // -- projection: D[r-tile, p-tile], 3-term split MFMA ----------------
        const int wbase = wv * 32;
        f32x4 acc[2][4] = {};
        #pragma unroll
        for (int k = 0; k < 2; ++k) {
            u16x8 ah[2], al[2];
            #pragma unroll
            for (int rt = 0; rt < 2; ++rt) {
                int row = wbase + rt * 16 + l16;
                int gk  = (quad + k * 4) ^ (row & 3);
                ah[rt] = *(const u16x8*)(hiP + row * 64 + gk * 8);
                al[rt] = *(const u16x8*)(loP + row * 64 + gk * 8);
            }
            #pragma unroll
            for (int pt = 0; pt < 4; ++pt) {
                int side = pt >> 1, ph = pt & 1;
                int hrow = ((side * 2 + 0) * 32 + ph * 16 + l16) * 72 + (quad + k * 4) * 8;
                int lrow = ((side * 2 + 1) * 32 + ph * 16 + l16) * 72 + (quad + k * 4) * 8;
                u16x8 bh = *(const u16x8*)(WP + hrow);
                u16x8 bl = *(const u16x8*)(WP + lrow);
                #pragma unroll
                for (int rt = 0; rt < 2; ++rt) {
                    acc[rt][pt] = __builtin_amdgcn_mfma_f32_16x16x32_bf16(
                        (s16x8)ah[rt], (s16x8)bh, acc[rt][pt], 0, 0, 0);
                    acc[rt][pt] = __builtin_amdgcn_mfma_f32_16x16x32_bf16(
                        (s16x8)al[rt], (s16x8)bh, acc[rt][pt], 0, 0, 0);
                    acc[rt][pt] = __builtin_amdgcn_mfma_f32_16x16x32_bf16(
                        (s16x8)ah[rt], (s16x8)bl, acc[rt][pt], 0, 0, 0);
                }
            }
        }

        // -- epilogue: left/right = mask*(proj + bias), u16x4 stores ---------
        #pragma unroll
        for (int rt = 0; rt < 2; ++rt) {
            int rowb = wbase + rt * 16 + quad * 4;        // rg 0..3 -> same ii
            f32x4 mk4 = *(const f32x4*)(mkP + rowb);
            int ii = rowb >> 3, sb = rowb & 7;            // sb in {0,4}
            #pragma unroll
            for (int pt = 0; pt < 4; ++pt) {
                int side = pt >> 1, p = (pt & 1) * 16 + l16;
                float bv = biasP[side * 32 + p];
                u16x4 ov;
                #pragma unroll
                for (int rg = 0; rg < 4; ++rg)
                    ov[rg] = f2b((acc[rt][pt][rg] + bv) * mk4[rg]);
                u16* dst = (side ? rightT : leftT)
                         + ((long)(i0 + ii) * NP + p) * NSEQ + s0 + sb;
                *(u16x4*)dst = ov;
            }
        }

    } else if (b < 896) {
        // ---------------- Wo f32 -> bf16, k'-permuted (unchanged) -----------
        int idx = (b - 768) * 256 + t;                 // [0, 32768)
        int o   = idx >> 8;
        int kp  = (idx & 255) << 2;
        int l16 = (kp >> 2) & 15;
        int ntb = (kp >> 6) & 1;
        int qd  = (kp >> 7) & 3;
        int mtb = (kp >> 9) & 1;
        const float* src = Wo + o * 1024 + (mtb * 16 + qd * 4) * 32 + ntb * 16 + l16;
        u16x4 w;
        #pragma unroll
        for (int rg = 0; rg < 4; ++rg) w[rg] = f2b(src[rg * 32]);
        *(u16x4*)(WoB + o * 1024 + kp) = w;

    } else {
        // ---------------- norm[i][j] = sum_s mask[s][i]*mask[s][j] ----------
        float (*mi)[17] = (float (*)[17])sm;
        float (*mj)[17] = (float (*)[17])(sm + 17408);
        const int bn = b - 896;
        const int iB = (bn / 24) * 16, jB = (bn % 24) * 16;
        #pragma unroll
        for (int it = 0; it < 16; ++it) {
            int ss = it * 16 + (t >> 4);
            int c  = t & 15;
            mi[ss][c] = mask[(long)ss * NRES + iB + c];
            mj[ss][c] = mask[(long)ss * NRES + jB + c];
        }
        __syncthreads();
        const int ti = t >> 4, tj = t & 15;
        float acc = 0.f;
        for (int ss = 0; ss < 256; ++ss) acc += mi[ss][ti] * mj[ss][tj];
        normMat[(long)(iB + ti) * NRES + jB + tj] = acc;
    }
}

// ---------------------------------------------------------------------------
// k_main: 256x128 tile, 8 waves, counted-vmcnt pipeline (unchanged core) +
// T5 setprio around MFMA clusters (2 blocks/CU give inter-block role split).
// ---------------------------------------------------------------------------
__global__ __launch_bounds__(512, 4) void k_main(
    const u16* __restrict__ leftT, const u16* __restrict__ rightT,
    const float* __restrict__ normMat,
    const u16* __restrict__ WoB, const float* __restrict__ bo,
    const float* __restrict__ Zraw, float* __restrict__ out)
{
    __shared__ __align__(16) u16 smem[32768];

    const int t    = threadIdx.x;
    const int wave = t >> 6, lane = t & 63;
    const int quad = lane >> 4, l16 = lane & 15;
    const int wr = wave >> 1, wc = wave & 1;

    const int bid = blockIdx.x;
    const int r_  = bid >> 3;
    const int bx  = r_ / 12;
    const int by  = (bid & 7) * 12 + (r_ % 12);
    const int icBase = bx * 256;
    const int jdBase = by * 128;

    const int srow = lane >> 2;
    const int g8   = ((lane & 3) ^ ((srow >> 1) & 3)) * 8;

    f32x4 acc[4][4] = {};

    const u16* aSrc0 = leftT  + (icBase + wave * 32 + srow) * NSEQ + g8;
    const u16* aSrc1 = aSrc0 + 16 * NSEQ;
    const u16* bSrc  = rightT + (jdBase + wave * 16 + srow) * NSEQ + g8;

    #define STAGE(buf, k0) do {                                                  \
        gload_lds16(aSrc0 + (k0), &smem[(buf) * 8192 + wave * 1024]);            \
        gload_lds16(aSrc1 + (k0), &smem[(buf) * 8192 + wave * 1024 + 512]);      \
        gload_lds16(bSrc  + (k0), &smem[16384 + (buf) * 4096 + wave * 512]);     \
    } while (0)

    STAGE(0, 0);

    #pragma unroll
    for (int kt = 0; kt < 8; ++kt) {
        const int cur = kt & 1;
        if (kt < 7) {
            STAGE(cur ^ 1, (kt + 1) * 32);
            asm volatile("s_waitcnt vmcnt(3)" ::: "memory");
        } else {
            asm volatile("s_waitcnt vmcnt(0)" ::: "memory");
        }
        __builtin_amdgcn_s_barrier();
        __builtin_amdgcn_sched_barrier(0);

        const int gx = (quad ^ ((l16 >> 1) & 3)) * 8;
        u16x8 af[4], bf[4];
        const u16* Ab = &smem[cur * 8192 + (wr * 64 + l16) * 32 + gx];
        const u16* Bb = &smem[16384 + cur * 4096 + (wc * 64 + l16) * 32 + gx];
        #pragma unroll
        for (int mt = 0; mt < 4; ++mt) af[mt] = *(const u16x8*)(Ab + mt * 512);
        #pragma unroll
        for (int nt = 0; nt < 4; ++nt) bf[nt] = *(const u16x8*)(Bb + nt * 512);

        __builtin_amdgcn_s_setprio(1);
        #pragma unroll
        for (int mt = 0; mt < 4; ++mt)
            #pragma unroll
            for (int nt = 0; nt < 4; ++nt)
                acc[mt][nt] = __builtin_amdgcn_mfma_f32_16x16x32_bf16(
                    (s16x8)af[mt], (s16x8)bf[nt], acc[mt][nt], 0, 0, 0);
        __builtin_amdgcn_s_setprio(0);

        __builtin_amdgcn_sched_barrier(0);
        __builtin_amdgcn_s_barrier();
    }
    #undef STAGE

    // ---- O tile -> Os overlay [pair][k'], swizzled -------------------------
    #pragma unroll
    for (int mt = 0; mt < 4; ++mt) {
        #pragma unroll
        for (int nt = 0; nt < 4; ++nt) {
            int pair = (wr * 2 + (mt >> 1)) * 4 + wc * 2 + (nt >> 1);
            int kp   = l16 * 4 + (nt & 1) * 64 + quad * 128 + (mt & 1) * 512;
            int ks   = kp ^ (quad << 4) ^ ((pair & 7) << 3);
            u16x4 wv;
            #pragma unroll
            for (int rg = 0; rg < 4; ++rg) wv[rg] = f2b(acc[mt][nt][rg]);
            *(u16x4*)&smem[pair * 1024 + ks] = wv;
        }
    }
    __syncthreads();

    // ---- stage 2: Z2[pair][o], shared Wo B-frag ----------------------------
    f32x4 acc2[2] = {};
    const int ob   = wave * 16;
    const int pxor = (l16 & 7) << 3;
    const u16* wp  = WoB + (ob + l16) * 1024 + quad * 8;
    const u16* os0 = &smem[l16 * 1024];
    const u16* os1 = &smem[(16 + l16) * 1024];
    #pragma unroll 8
    for (int kk = 0; kk < 32; ++kk) {
        int kp = kk * 32 + quad * 8;
        int ks = kp ^ (((kp >> 7) & 3) << 4) ^ pxor;
        u16x8 a0 = *(const u16x8*)(os0 + ks);
        u16x8 a1 = *(const u16x8*)(os1 + ks);
        u16x8 bv = *(const u16x8*)(wp + kk * 32);
        __builtin_amdgcn_s_setprio(1);
        acc2[0] = __builtin_amdgcn_mfma_f32_16x16x32_bf16((s16x8)a0, (s16x8)bv, acc2[0], 0, 0, 0);
        acc2[1] = __builtin_amdgcn_mfma_f32_16x16x32_bf16((s16x8)a1, (s16x8)bv, acc2[1], 0, 0, 0);
        __builtin_amdgcn_s_setprio(0);
    }
    __syncthreads();

    // ---- Z2 -> LDS f32 [32][128] for coalesced epilogue --------------------
    float* zs = (float*)smem;
    #pragma unroll
    for (int m = 0; m < 2; ++m)
        #pragma unroll
        for (int rg = 0; rg < 4; ++rg)
            zs[(m * 16 + quad * 4 + rg) * 128 + ob + l16] = acc2[m][rg];
    __syncthreads();

    // ---- epilogue ----------------------------------------------------------
    const int i0 = bx * 8, j0 = by * 4;
    const int pr = t >> 4, o0 = (t & 15) * 8;
    const int i = i0 + (pr >> 2), j = j0 + (pr & 3);
    const float rn = 1.f / (0.001f + normMat[i * NRES + j]);
    const long base = ((long)(i * NRES + j)) * NO + o0;
    f32x4 z0  = *(const f32x4*)&zs[pr * 128 + o0];
    f32x4 z1  = *(const f32x4*)&zs[pr * 128 + o0 + 4];
    f32x4 zr0 = *(const f32x4*)(Zraw + base);
    f32x4 zr1 = *(const f32x4*)(Zraw + base + 4);
    f32x4 bv0 = *(const f32x4*)(bo + o0);
    f32x4 bv1 = *(const f32x4*)(bo + o0 + 4);
    f32x4 r0, r1;
    #pragma unroll
    for (int e = 0; e < 4; ++e) r0[e] = (z0[e] + bv0[e]) * rn + zr0[e];
    #pragma unroll
    for (int e = 0; e < 4; ++e) r1[e] = (z1[e] + bv1[e]) * rn + zr1[e];
    *(f32x4*)(out + base)     = r0;
    *(f32x4*)(out + base + 4) = r1;
}

extern "C" void kernel_launch(void* const* d_in, const int* in_sizes, int n_in,
                              void* d_out, int out_size, void* d_ws, size_t ws_size,
                              hipStream_t stream)
{
    const float* M     = (const float*)d_in[0];
    const float* mask  = (const float*)d_in[1];
    const float* Zraw  = (const float*)d_in[2];
    const float* gamma = (const float*)d_in[3];
    const float* beta  = (const float*)d_in[4];
    const float* Wa    = (const float*)d_in[5];
    const float* ba    = (const float*)d_in[6];
    const float* Wb    = (const float*)d_in[7];
    const float* bb    = (const float*)d_in[8];
    const float* Wo    = (const float*)d_in[9];
    const float* bo    = (const float*)d_in[10];
    float* out = (float*)d_out;

    char* ws = (char*)d_ws;
    u16*   leftT   = (u16*)ws;                      // 12288 x 256 bf16
    u16*   rightT  = (u16*)(ws + 6291456);
    float* normMat = (float*)(ws + 12582912);       // 384x384 f32
    u16*   WoB     = (u16*)(ws + 13172736);         // 128x1024 bf16 (k'-permuted)

    k_pre<<<dim3(1472), dim3(256), 0, stream>>>(M, mask, gamma, beta,
                                                Wa, ba, Wb, bb, Wo,
                                                leftT, rightT, normMat, WoB);
    k_main<<<dim3(4608), dim3(512), 0, stream>>>(leftT, rightT, normMat,
                                                 WoB, bo, Zraw, out);
}